// Round 13
// baseline (163.141 us; speedup 1.0000x reference)
//
#include <hip/hip_runtime.h>
#include <cmath>

#define B_ 4
#define N_ 512
#define F_ 128
#define BN_ (B_*N_)   // 2048
#define NG_ (BN_/4)   // 512 row-groups of 4

__device__ __forceinline__ float elu_f(float x) {
    return fmaxf(x, __expf(fminf(x, 0.f)) - 1.f);
}

// ---------------------------------------------------------------------------
// Kernel 1 (544 blocks x 512 thr):
//  blocks [0,512):   lin1 for 4 rows — Hi = H@dW1[:F]+db1, EHi = exp(Hi),
//                    HjT[b][f][n] = (H@dW1[F:])^T. K split across kq=t>>7.
//  blocks [512,544): colsum partials: csp[b][e][f] = sum of 64 H rows.
// ---------------------------------------------------------------------------
__global__ __launch_bounds__(512, 4) void k_pre(
    const float* __restrict__ H, const float* __restrict__ dW1,
    const float* __restrict__ db1,
    float* __restrict__ Hi, float* __restrict__ EHi, float* __restrict__ HjT,
    float* __restrict__ csp) {
    __shared__ float sH[4][F_];
    __shared__ float sPA[3][4][F_], sPB[3][4][F_];
    const int t = threadIdx.x;
    const int f = t & 127;
    const int kq = t >> 7;
    if (blockIdx.x < NG_) {
        // ---------------- lin1 ----------------
        const int row0 = blockIdx.x * 4;
        const int b  = row0 >> 9;
        const int n0 = row0 & 511;
        sH[kq][f] = H[(size_t)(row0 + kq) * F_ + f];
        __syncthreads();
        float accA[4] = {0.f,0.f,0.f,0.f}, accB[4] = {0.f,0.f,0.f,0.f};
        const int k0 = kq * 32;
        #pragma unroll 4
        for (int k = k0; k < k0 + 32; ++k) {
            const float wa = dW1[(size_t)k * F_ + f];
            const float wb = dW1[(size_t)(F_ + k) * F_ + f];
            #pragma unroll
            for (int r = 0; r < 4; ++r) {
                accA[r] = fmaf(sH[r][k], wa, accA[r]);
                accB[r] = fmaf(sH[r][k], wb, accB[r]);
            }
        }
        if (kq > 0) {
            #pragma unroll
            for (int r = 0; r < 4; ++r) {
                sPA[kq - 1][r][f] = accA[r];
                sPB[kq - 1][r][f] = accB[r];
            }
        }
        __syncthreads();
        if (kq == 0) {
            const float bias = db1[f];
            float bsum[4];
            #pragma unroll
            for (int r = 0; r < 4; ++r) {
                const float av = accA[r] + sPA[0][r][f] + sPA[1][r][f]
                               + sPA[2][r][f] + bias;
                Hi [(size_t)(row0 + r) * F_ + f] = av;
                EHi[(size_t)(row0 + r) * F_ + f] = __expf(av);
                bsum[r] = accB[r] + sPB[0][r][f] + sPB[1][r][f] + sPB[2][r][f];
            }
            float4 hv;
            hv.x = bsum[0]; hv.y = bsum[1]; hv.z = bsum[2]; hv.w = bsum[3];
            *reinterpret_cast<float4*>(HjT + ((size_t)b * F_ + f) * N_ + n0) = hv;
        }
    } else {
        // ---------------- colsum partial ----------------
        const int bx = blockIdx.x - NG_;   // 0..31
        const int b  = bx >> 3;
        const int e  = bx & 7;             // batch-eighth (64 rows)
        float s = 0.f;
        const float* hp = H + ((size_t)b * N_ + e * 64 + kq * 16) * F_ + f;
        #pragma unroll 4
        for (int jj = 0; jj < 16; ++jj) s += hp[(size_t)jj * F_];
        sH[kq][f] = s;
        __syncthreads();
        if (kq == 0)
            csp[((size_t)b * 8 + e) * F_ + f] =
                sH[0][f] + sH[1][f] + sH[2][f] + sH[3][f];
    }
}

// one f-slice: uniforms = component CP of (h0..h3, e0..e3, wq); 4 j's = HJ4.
// All accesses static components — no address-of, no dynamic indexing.
#define SCORE_F(HJ4, CP) {                                                    \
    const float ejx = __expf((HJ4).x), ejy = __expf((HJ4).y),                 \
                ejz = __expf((HJ4).z), ejw = __expf((HJ4).w);                 \
    const float wv_ = wq.CP;                                                  \
    acc0.x = fmaf(__builtin_amdgcn_fmed3f(h0.CP + (HJ4).x, fmaf(e0.CP, ejx, -1.f), 0.f), wv_, acc0.x); \
    acc0.y = fmaf(__builtin_amdgcn_fmed3f(h0.CP + (HJ4).y, fmaf(e0.CP, ejy, -1.f), 0.f), wv_, acc0.y); \
    acc0.z = fmaf(__builtin_amdgcn_fmed3f(h0.CP + (HJ4).z, fmaf(e0.CP, ejz, -1.f), 0.f), wv_, acc0.z); \
    acc0.w = fmaf(__builtin_amdgcn_fmed3f(h0.CP + (HJ4).w, fmaf(e0.CP, ejw, -1.f), 0.f), wv_, acc0.w); \
    acc1.x = fmaf(__builtin_amdgcn_fmed3f(h1.CP + (HJ4).x, fmaf(e1.CP, ejx, -1.f), 0.f), wv_, acc1.x); \
    acc1.y = fmaf(__builtin_amdgcn_fmed3f(h1.CP + (HJ4).y, fmaf(e1.CP, ejy, -1.f), 0.f), wv_, acc1.y); \
    acc1.z = fmaf(__builtin_amdgcn_fmed3f(h1.CP + (HJ4).z, fmaf(e1.CP, ejz, -1.f), 0.f), wv_, acc1.z); \
    acc1.w = fmaf(__builtin_amdgcn_fmed3f(h1.CP + (HJ4).w, fmaf(e1.CP, ejw, -1.f), 0.f), wv_, acc1.w); \
    acc2.x = fmaf(__builtin_amdgcn_fmed3f(h2.CP + (HJ4).x, fmaf(e2.CP, ejx, -1.f), 0.f), wv_, acc2.x); \
    acc2.y = fmaf(__builtin_amdgcn_fmed3f(h2.CP + (HJ4).y, fmaf(e2.CP, ejy, -1.f), 0.f), wv_, acc2.y); \
    acc2.z = fmaf(__builtin_amdgcn_fmed3f(h2.CP + (HJ4).z, fmaf(e2.CP, ejz, -1.f), 0.f), wv_, acc2.z); \
    acc2.w = fmaf(__builtin_amdgcn_fmed3f(h2.CP + (HJ4).w, fmaf(e2.CP, ejw, -1.f), 0.f), wv_, acc2.w); \
    acc3.x = fmaf(__builtin_amdgcn_fmed3f(h3.CP + (HJ4).x, fmaf(e3.CP, ejx, -1.f), 0.f), wv_, acc3.x); \
    acc3.y = fmaf(__builtin_amdgcn_fmed3f(h3.CP + (HJ4).y, fmaf(e3.CP, ejy, -1.f), 0.f), wv_, acc3.y); \
    acc3.z = fmaf(__builtin_amdgcn_fmed3f(h3.CP + (HJ4).z, fmaf(e3.CP, ejz, -1.f), 0.f), wv_, acc3.z); \
    acc3.w = fmaf(__builtin_amdgcn_fmed3f(h3.CP + (HJ4).w, fmaf(e3.CP, ejw, -1.f), 0.f), wv_, acc3.w); }

// ---------------------------------------------------------------------------
// Kernel 2: score. 4 rows/block, 512 blocks x 512 thr.
// Thread (kq=t>>7, u=t&127) owns j-quad [4u..4u+3] x f-range [kq*32, +32):
// b128 hj loads, each sU quad read serves 64 elems, each exp serves 16.
// Cross-kq partials via conflict-free sAcc[kq][r][j]; then mask/ballot/max
// in the t=j layout (identical to the verified R11 logic).
// ---------------------------------------------------------------------------
__global__ __launch_bounds__(512, 4) void k_score(
    const float* __restrict__ Hi, const float* __restrict__ EHi,
    const float* __restrict__ HjT, const float* __restrict__ A,
    const float* __restrict__ dW2, const float* __restrict__ db2,
    float* __restrict__ maxcv, float* __restrict__ degv,
    unsigned long long* __restrict__ zmask, float* __restrict__ maskout) {
    __shared__ float4 sU[32][9];          // [quad][0..3]=hi rows,[4..7]=Ei,[8]=w
    __shared__ float  sAcc[4][4][N_];     // [kq][r][j] partial logits (32 KB)
    __shared__ float  red_mx[8][4];
    __shared__ int    red_cnt[8][4];
    const int t = threadIdx.x;
    const int lane = t & 63;
    const int w = t >> 6;                 // wave 0..7
    const int u  = t & 127;               // j-quad owner
    const int kq = t >> 7;                // f-range owner
    const int bi0 = blockIdx.x * 4;
    const int b = bi0 >> 9;

    if (t < 288) {
        const int q  = t / 9;
        const int sl = t - q * 9;
        const float* src = (sl < 4) ? (Hi  + (size_t)(bi0 + sl)     * F_ + 4 * q)
                         : (sl < 8) ? (EHi + (size_t)(bi0 + sl - 4) * F_ + 4 * q)
                                    : (dW2 + 4 * q);
        sU[q][sl] = *reinterpret_cast<const float4*>(src);
    }
    float a_r[4];
    #pragma unroll
    for (int r = 0; r < 4; ++r) a_r[r] = A[(size_t)(bi0 + r) * N_ + t];

    // hj base: f = kq*32, j = 4u
    const float* __restrict__ hjq = HjT + (size_t)b * F_ * N_
                                  + (size_t)(kq * 32) * N_ + 4 * u;
    float4 hjA[4], hjB[4];
    #pragma unroll
    for (int s = 0; s < 4; ++s)
        hjA[s] = *reinterpret_cast<const float4*>(hjq + (size_t)s * N_);
    __syncthreads();

    float4 acc0 = {0.f,0.f,0.f,0.f}, acc1 = {0.f,0.f,0.f,0.f};
    float4 acc2 = {0.f,0.f,0.f,0.f}, acc3 = {0.f,0.f,0.f,0.f};

    auto compQ = [&](int qq, const float4 (&hjv)[4]) {
        const int q = kq * 8 + qq;
        const float4 h0 = sU[q][0], h1 = sU[q][1], h2 = sU[q][2], h3 = sU[q][3];
        const float4 e0 = sU[q][4], e1 = sU[q][5], e2 = sU[q][6], e3 = sU[q][7];
        const float4 wq = sU[q][8];
        SCORE_F(hjv[0], x)
        SCORE_F(hjv[1], y)
        SCORE_F(hjv[2], z)
        SCORE_F(hjv[3], w)
    };
    auto loadQ = [&](int qq, float4 (&buf)[4]) {
        #pragma unroll
        for (int s = 0; s < 4; ++s)
            buf[s] = *reinterpret_cast<const float4*>(
                hjq + (size_t)(qq * 4 + s) * N_);
    };

    #pragma unroll
    for (int qq = 0; qq < 8; qq += 2) {
        loadQ(qq + 1, hjB);
        compQ(qq, hjA);
        if (qq + 2 < 8) loadQ(qq + 2, hjA);
        compQ(qq + 1, hjB);
    }

    // spill partial sums: conflict-free b128 writes, [kq][r][j] layout
    *reinterpret_cast<float4*>(&sAcc[kq][0][4 * u]) = acc0;
    *reinterpret_cast<float4*>(&sAcc[kq][1][4 * u]) = acc1;
    *reinterpret_cast<float4*>(&sAcc[kq][2][4 * u]) = acc2;
    *reinterpret_cast<float4*>(&sAcc[kq][3][4 * u]) = acc3;
    __syncthreads();

    // back to t = j layout: sum over kq, mask, ballot, wave-reduce
    #pragma unroll
    for (int r = 0; r < 4; ++r) {
        const float a = a_r[r];
        const float sum = sAcc[0][r][t] + sAcc[1][r][t]
                        + sAcc[2][r][t] + sAcc[3][r][t];
        float mx = (a > 0.1f) ? sum : -INFINITY;
        #pragma unroll
        for (int off = 1; off < 64; off <<= 1)
            mx = fmaxf(mx, __shfl_xor(mx, off));
        const unsigned long long pos = __ballot(a > 0.f);
        const unsigned long long zb  = __ballot(a <= 0.f);
        if (lane == 0) {
            red_mx[w][r]  = mx;
            red_cnt[w][r] = (int)__popcll(pos);
            zmask[(size_t)(bi0 + r) * 8 + w] = zb;
        }
    }
    __syncthreads();
    if (t < 4) {
        float m = -INFINITY; int c = 0;
        #pragma unroll
        for (int ww = 0; ww < 8; ++ww) {
            m = fmaxf(m, red_mx[ww][t]);
            c += red_cnt[ww][t];
        }
        const float mc = (m > -INFINITY)
                       ? 1.f / (1.f + __expf(-(m + db2[0]))) : 0.f;
        maxcv[bi0 + t] = mc;
        degv[bi0 + t]  = (float)c;
        maskout[bi0 + t] = (mc > 0.5f) ? 1.f : 0.f;
    }
}

// ---------------------------------------------------------------------------
// Kernel 3: row MLP. 4 rows/block, 512 blocks x 512 thr; f=t&127, kq=t>>7.
// nf = (colsum - sum of A<=0 exception rows) / deg.
// ---------------------------------------------------------------------------
__global__ __launch_bounds__(512, 4) void k_mlp(
    const float* __restrict__ H, const float* __restrict__ csp,
    const unsigned long long* __restrict__ zmask,
    const float* __restrict__ degv, const float* __restrict__ maxcv,
    const float* __restrict__ rW1, const float* __restrict__ rb1,
    const float* __restrict__ rW2, const float* __restrict__ rb2,
    float* __restrict__ out) {
    __shared__ float sC[4][260];
    __shared__ float sP[3][4][F_];
    __shared__ float sL1[4][F_];
    __shared__ float sMC[4], sDegF[4];
    const int t  = threadIdx.x;
    const int f  = t & 127;
    const int kq = t >> 7;
    const int row0 = blockIdx.x * 4;
    const int b = row0 >> 9;

    {   // stage H + assembled nf (thread's row = kq)
        const int row = row0 + kq;
        sC[kq][f] = H[(size_t)row * F_ + f];
        float cs = 0.f;
        #pragma unroll
        for (int e = 0; e < 8; ++e)
            cs += csp[((size_t)b * 8 + e) * F_ + f];
        #pragma unroll
        for (int wv = 0; wv < 8; ++wv) {
            unsigned long long zb = zmask[(size_t)row * 8 + wv];
            while (zb) {                    // uniform loop; empty in practice
                const int j = __ffsll(zb) - 1;
                zb &= zb - 1;
                cs -= H[((size_t)b * N_ + wv * 64 + j) * F_ + f];
            }
        }
        sC[kq][F_ + f] = cs / fmaxf(degv[row], 1.f);
    }
    if (t < 4) {
        sMC[t]   = maxcv[row0 + t];
        sDegF[t] = degv[row0 + t];
    }
    __syncthreads();

    // ---- layer 1 ----
    float macc[4];
    {
        const float bias = rb1[f];
        #pragma unroll
        for (int r = 0; r < 4; ++r) macc[r] = (kq == 0) ? bias : 0.f;
    }
    const int k0 = kq * 64;
    #pragma unroll 4
    for (int k = k0; k < k0 + 64; ++k) {
        const float wv = rW1[(size_t)k * F_ + f];
        #pragma unroll
        for (int r = 0; r < 4; ++r) macc[r] = fmaf(sC[r][k], wv, macc[r]);
    }
    if (kq == 3) {
        const float w256 = rW1[(size_t)256 * F_ + f];
        #pragma unroll
        for (int r = 0; r < 4; ++r) macc[r] = fmaf(sMC[r], w256, macc[r]);
    }
    if (kq > 0) {
        #pragma unroll
        for (int r = 0; r < 4; ++r) sP[kq - 1][r][f] = macc[r];
    }
    __syncthreads();
    if (kq == 0) {
        #pragma unroll
        for (int r = 0; r < 4; ++r)
            sL1[r][f] = elu_f(macc[r] + sP[0][r][f] + sP[1][r][f] + sP[2][r][f]);
    }
    __syncthreads();

    // ---- layer 2 ----
    float macc2[4];
    {
        const float bias2 = rb2[f];
        #pragma unroll
        for (int r = 0; r < 4; ++r) macc2[r] = (kq == 0) ? bias2 : 0.f;
    }
    const int m0k = kq * 32;
    #pragma unroll 4
    for (int k = m0k; k < m0k + 32; ++k) {
        const float wv = rW2[(size_t)k * F_ + f];
        #pragma unroll
        for (int r = 0; r < 4; ++r) macc2[r] = fmaf(sL1[r][k], wv, macc2[r]);
    }
    if (kq > 0) {
        #pragma unroll
        for (int r = 0; r < 4; ++r) sP[kq - 1][r][f] = macc2[r];
    }
    __syncthreads();
    if (kq == 0) {
        #pragma unroll
        for (int r = 0; r < 4; ++r) {
            const int row = row0 + r;
            const float res = macc2[r] + sP[0][r][f] + sP[1][r][f] + sP[2][r][f];
            const bool upd = (sMC[r] > 0.5f) && (sDegF[r] > 0.f);
            out[(size_t)row * F_ + f] = upd ? res : sC[r][f];
        }
    }
}

// ---------------------------------------------------------------------------
extern "C" void kernel_launch(void* const* d_in, const int* in_sizes, int n_in,
                              void* d_out, int out_size, void* d_ws, size_t ws_size,
                              hipStream_t stream) {
    const float* H   = (const float*)d_in[0];
    const float* A   = (const float*)d_in[1];
    const float* dW1 = (const float*)d_in[2];
    const float* db1 = (const float*)d_in[3];
    const float* dW2 = (const float*)d_in[4];
    const float* db2 = (const float*)d_in[5];
    const float* rW1 = (const float*)d_in[6];
    const float* rb1 = (const float*)d_in[7];
    const float* rW2 = (const float*)d_in[8];
    const float* rb2 = (const float*)d_in[9];

    float* ws   = (float*)d_ws;
    float* Hi   = ws;                        // [BN][F]
    float* EHi  = Hi   + BN_ * F_;           // [BN][F]
    float* HjT  = EHi  + BN_ * F_;           // [B][F][N]
    float* csp  = HjT  + BN_ * F_;           // [B][8][F] colsum partials
    float* degv = csp  + B_ * 8 * F_;        // [BN]
    float* maxc = degv + BN_;                // [BN]
    unsigned long long* zmask =
        (unsigned long long*)(maxc + BN_);   // [BN][8]

    float* out      = (float*)d_out;         // [BN][F]
    float* mask_out = out + BN_ * F_;        // [BN]

    k_pre  <<<NG_ + 32, 512, 0, stream>>>(H, dW1, db1, Hi, EHi, HjT, csp);
    k_score<<<NG_, 512, 0, stream>>>(Hi, EHi, HjT, A, dW2, db2,
                                     maxc, degv, zmask, mask_out);
    k_mlp  <<<NG_, 512, 0, stream>>>(H, csp, zmask, degv, maxc,
                                     rW1, rb1, rW2, rb2, out);
}

// Round 14
// 135.130 us; speedup vs baseline: 1.2073x; 1.2073x over previous
//
#include <hip/hip_runtime.h>
#include <cmath>

#define B_ 4
#define N_ 512
#define F_ 128
#define BN_ (B_*N_)   // 2048
#define NG_ (BN_/4)   // 512 row-groups of 4

__device__ __forceinline__ float elu_f(float x) {
    return fmaxf(x, __expf(fminf(x, 0.f)) - 1.f);
}

// ---------------------------------------------------------------------------
// Kernel 1 (544 blocks x 512 thr):
//  blocks [0,512):   lin1 for 4 rows — Hi = H@dW1[:F]+db1, EHi = exp(Hi),
//                    HjT[b][f][n] = (H@dW1[F:])^T. K split across kq=t>>7.
//  blocks [512,544): colsum partials: csp[b][e][f] = sum of 64 H rows.
// ---------------------------------------------------------------------------
__global__ __launch_bounds__(512, 4) void k_pre(
    const float* __restrict__ H, const float* __restrict__ dW1,
    const float* __restrict__ db1,
    float* __restrict__ Hi, float* __restrict__ EHi, float* __restrict__ HjT,
    float* __restrict__ csp) {
    __shared__ float sH[4][F_];
    __shared__ float sPA[3][4][F_], sPB[3][4][F_];
    const int t = threadIdx.x;
    const int f = t & 127;
    const int kq = t >> 7;
    if (blockIdx.x < NG_) {
        // ---------------- lin1 ----------------
        const int row0 = blockIdx.x * 4;
        const int b  = row0 >> 9;
        const int n0 = row0 & 511;
        sH[kq][f] = H[(size_t)(row0 + kq) * F_ + f];
        __syncthreads();
        float accA[4] = {0.f,0.f,0.f,0.f}, accB[4] = {0.f,0.f,0.f,0.f};
        const int k0 = kq * 32;
        #pragma unroll 4
        for (int k = k0; k < k0 + 32; ++k) {
            const float wa = dW1[(size_t)k * F_ + f];
            const float wb = dW1[(size_t)(F_ + k) * F_ + f];
            #pragma unroll
            for (int r = 0; r < 4; ++r) {
                accA[r] = fmaf(sH[r][k], wa, accA[r]);
                accB[r] = fmaf(sH[r][k], wb, accB[r]);
            }
        }
        if (kq > 0) {
            #pragma unroll
            for (int r = 0; r < 4; ++r) {
                sPA[kq - 1][r][f] = accA[r];
                sPB[kq - 1][r][f] = accB[r];
            }
        }
        __syncthreads();
        if (kq == 0) {
            const float bias = db1[f];
            float bsum[4];
            #pragma unroll
            for (int r = 0; r < 4; ++r) {
                const float av = accA[r] + sPA[0][r][f] + sPA[1][r][f]
                               + sPA[2][r][f] + bias;
                Hi [(size_t)(row0 + r) * F_ + f] = av;
                EHi[(size_t)(row0 + r) * F_ + f] = __expf(av);
                bsum[r] = accB[r] + sPB[0][r][f] + sPB[1][r][f] + sPB[2][r][f];
            }
            float4 hv;
            hv.x = bsum[0]; hv.y = bsum[1]; hv.z = bsum[2]; hv.w = bsum[3];
            *reinterpret_cast<float4*>(HjT + ((size_t)b * F_ + f) * N_ + n0) = hv;
        }
    } else {
        // ---------------- colsum partial ----------------
        const int bx = blockIdx.x - NG_;   // 0..31
        const int b  = bx >> 3;
        const int e  = bx & 7;             // batch-eighth (64 rows)
        float s = 0.f;
        const float* hp = H + ((size_t)b * N_ + e * 64 + kq * 16) * F_ + f;
        #pragma unroll 4
        for (int jj = 0; jj < 16; ++jj) s += hp[(size_t)jj * F_];
        sH[kq][f] = s;
        __syncthreads();
        if (kq == 0)
            csp[((size_t)b * 8 + e) * F_ + f] =
                sH[0][f] + sH[1][f] + sH[2][f] + sH[3][f];
    }
}

// one f-slice: uniforms = component CP of (h0..h3, e0..e3, wq); 4 j's = HJ4.
#define SCORE_F(HJ4, CP) {                                                    \
    const float ejx = __expf((HJ4).x), ejy = __expf((HJ4).y),                 \
                ejz = __expf((HJ4).z), ejw = __expf((HJ4).w);                 \
    const float wv_ = wq.CP;                                                  \
    acc0.x = fmaf(__builtin_amdgcn_fmed3f(h0.CP + (HJ4).x, fmaf(e0.CP, ejx, -1.f), 0.f), wv_, acc0.x); \
    acc0.y = fmaf(__builtin_amdgcn_fmed3f(h0.CP + (HJ4).y, fmaf(e0.CP, ejy, -1.f), 0.f), wv_, acc0.y); \
    acc0.z = fmaf(__builtin_amdgcn_fmed3f(h0.CP + (HJ4).z, fmaf(e0.CP, ejz, -1.f), 0.f), wv_, acc0.z); \
    acc0.w = fmaf(__builtin_amdgcn_fmed3f(h0.CP + (HJ4).w, fmaf(e0.CP, ejw, -1.f), 0.f), wv_, acc0.w); \
    acc1.x = fmaf(__builtin_amdgcn_fmed3f(h1.CP + (HJ4).x, fmaf(e1.CP, ejx, -1.f), 0.f), wv_, acc1.x); \
    acc1.y = fmaf(__builtin_amdgcn_fmed3f(h1.CP + (HJ4).y, fmaf(e1.CP, ejy, -1.f), 0.f), wv_, acc1.y); \
    acc1.z = fmaf(__builtin_amdgcn_fmed3f(h1.CP + (HJ4).z, fmaf(e1.CP, ejz, -1.f), 0.f), wv_, acc1.z); \
    acc1.w = fmaf(__builtin_amdgcn_fmed3f(h1.CP + (HJ4).w, fmaf(e1.CP, ejw, -1.f), 0.f), wv_, acc1.w); \
    acc2.x = fmaf(__builtin_amdgcn_fmed3f(h2.CP + (HJ4).x, fmaf(e2.CP, ejx, -1.f), 0.f), wv_, acc2.x); \
    acc2.y = fmaf(__builtin_amdgcn_fmed3f(h2.CP + (HJ4).y, fmaf(e2.CP, ejy, -1.f), 0.f), wv_, acc2.y); \
    acc2.z = fmaf(__builtin_amdgcn_fmed3f(h2.CP + (HJ4).z, fmaf(e2.CP, ejz, -1.f), 0.f), wv_, acc2.z); \
    acc2.w = fmaf(__builtin_amdgcn_fmed3f(h2.CP + (HJ4).w, fmaf(e2.CP, ejw, -1.f), 0.f), wv_, acc2.w); \
    acc3.x = fmaf(__builtin_amdgcn_fmed3f(h3.CP + (HJ4).x, fmaf(e3.CP, ejx, -1.f), 0.f), wv_, acc3.x); \
    acc3.y = fmaf(__builtin_amdgcn_fmed3f(h3.CP + (HJ4).y, fmaf(e3.CP, ejy, -1.f), 0.f), wv_, acc3.y); \
    acc3.z = fmaf(__builtin_amdgcn_fmed3f(h3.CP + (HJ4).z, fmaf(e3.CP, ejz, -1.f), 0.f), wv_, acc3.z); \
    acc3.w = fmaf(__builtin_amdgcn_fmed3f(h3.CP + (HJ4).w, fmaf(e3.CP, ejw, -1.f), 0.f), wv_, acc3.w); }

// load the 4 hj rows of quad QQ into 4 NAMED float4s (no arrays -> no scratch)
#define LOADQ(QQ, B0, B1, B2, B3)                                             \
    B0 = *reinterpret_cast<const float4*>(hjq + (size_t)((QQ) * 4 + 0) * N_); \
    B1 = *reinterpret_cast<const float4*>(hjq + (size_t)((QQ) * 4 + 1) * N_); \
    B2 = *reinterpret_cast<const float4*>(hjq + (size_t)((QQ) * 4 + 2) * N_); \
    B3 = *reinterpret_cast<const float4*>(hjq + (size_t)((QQ) * 4 + 3) * N_);

#define COMPQ(QQ, B0, B1, B2, B3) {                                           \
    const int q_ = kq * 8 + (QQ);                                             \
    const float4 h0 = sU[q_][0], h1 = sU[q_][1], h2 = sU[q_][2], h3 = sU[q_][3]; \
    const float4 e0 = sU[q_][4], e1 = sU[q_][5], e2 = sU[q_][6], e3 = sU[q_][7]; \
    const float4 wq = sU[q_][8];                                              \
    SCORE_F(B0, x) SCORE_F(B1, y) SCORE_F(B2, z) SCORE_F(B3, w) }

// ---------------------------------------------------------------------------
// Kernel 2: score. 4 rows/block, 512 blocks x 512 thr.
// Thread (kq=t>>7, u=t&127) owns j-quad [4u..4u+3] x f-range [kq*32, +32):
// b128 hj loads, each sU quad read serves 64 elems, each exp serves 16.
// hj double-buffer is 8 NAMED float4s, manually software-pipelined.
// ---------------------------------------------------------------------------
__global__ __launch_bounds__(512, 4) void k_score(
    const float* __restrict__ Hi, const float* __restrict__ EHi,
    const float* __restrict__ HjT, const float* __restrict__ A,
    const float* __restrict__ dW2, const float* __restrict__ db2,
    float* __restrict__ maxcv, float* __restrict__ degv,
    unsigned long long* __restrict__ zmask, float* __restrict__ maskout) {
    __shared__ float4 sU[32][9];          // [quad][0..3]=hi rows,[4..7]=Ei,[8]=w
    __shared__ float  sAcc[4][4][N_];     // [kq][r][j] partial logits (32 KB)
    __shared__ float  red_mx[8][4];
    __shared__ int    red_cnt[8][4];
    const int t = threadIdx.x;
    const int lane = t & 63;
    const int w = t >> 6;                 // wave 0..7
    const int u  = t & 127;               // j-quad owner
    const int kq = t >> 7;                // f-range owner
    const int bi0 = blockIdx.x * 4;
    const int b = bi0 >> 9;

    if (t < 288) {
        const int q  = t / 9;
        const int sl = t - q * 9;
        const float* src = (sl < 4) ? (Hi  + (size_t)(bi0 + sl)     * F_ + 4 * q)
                         : (sl < 8) ? (EHi + (size_t)(bi0 + sl - 4) * F_ + 4 * q)
                                    : (dW2 + 4 * q);
        sU[q][sl] = *reinterpret_cast<const float4*>(src);
    }
    float a_r[4];
    #pragma unroll
    for (int r = 0; r < 4; ++r) a_r[r] = A[(size_t)(bi0 + r) * N_ + t];

    // hj base: f = kq*32, j = 4u
    const float* __restrict__ hjq = HjT + (size_t)b * F_ * N_
                                  + (size_t)(kq * 32) * N_ + 4 * u;
    float4 hA0, hA1, hA2, hA3, hB0, hB1, hB2, hB3;
    LOADQ(0, hA0, hA1, hA2, hA3)
    __syncthreads();

    float4 acc0 = {0.f,0.f,0.f,0.f}, acc1 = {0.f,0.f,0.f,0.f};
    float4 acc2 = {0.f,0.f,0.f,0.f}, acc3 = {0.f,0.f,0.f,0.f};

    LOADQ(1, hB0, hB1, hB2, hB3)
    COMPQ(0, hA0, hA1, hA2, hA3)
    LOADQ(2, hA0, hA1, hA2, hA3)
    COMPQ(1, hB0, hB1, hB2, hB3)
    LOADQ(3, hB0, hB1, hB2, hB3)
    COMPQ(2, hA0, hA1, hA2, hA3)
    LOADQ(4, hA0, hA1, hA2, hA3)
    COMPQ(3, hB0, hB1, hB2, hB3)
    LOADQ(5, hB0, hB1, hB2, hB3)
    COMPQ(4, hA0, hA1, hA2, hA3)
    LOADQ(6, hA0, hA1, hA2, hA3)
    COMPQ(5, hB0, hB1, hB2, hB3)
    LOADQ(7, hB0, hB1, hB2, hB3)
    COMPQ(6, hA0, hA1, hA2, hA3)
    COMPQ(7, hB0, hB1, hB2, hB3)

    // spill partial sums: conflict-free b128 writes, [kq][r][j] layout
    *reinterpret_cast<float4*>(&sAcc[kq][0][4 * u]) = acc0;
    *reinterpret_cast<float4*>(&sAcc[kq][1][4 * u]) = acc1;
    *reinterpret_cast<float4*>(&sAcc[kq][2][4 * u]) = acc2;
    *reinterpret_cast<float4*>(&sAcc[kq][3][4 * u]) = acc3;
    __syncthreads();

    // back to t = j layout: sum over kq, mask, ballot, wave-reduce
    #pragma unroll
    for (int r = 0; r < 4; ++r) {
        const float a = a_r[r];
        const float sum = sAcc[0][r][t] + sAcc[1][r][t]
                        + sAcc[2][r][t] + sAcc[3][r][t];
        float mx = (a > 0.1f) ? sum : -INFINITY;
        #pragma unroll
        for (int off = 1; off < 64; off <<= 1)
            mx = fmaxf(mx, __shfl_xor(mx, off));
        const unsigned long long pos = __ballot(a > 0.f);
        const unsigned long long zb  = __ballot(a <= 0.f);
        if (lane == 0) {
            red_mx[w][r]  = mx;
            red_cnt[w][r] = (int)__popcll(pos);
            zmask[(size_t)(bi0 + r) * 8 + w] = zb;
        }
    }
    __syncthreads();
    if (t < 4) {
        float m = -INFINITY; int c = 0;
        #pragma unroll
        for (int ww = 0; ww < 8; ++ww) {
            m = fmaxf(m, red_mx[ww][t]);
            c += red_cnt[ww][t];
        }
        const float mc = (m > -INFINITY)
                       ? 1.f / (1.f + __expf(-(m + db2[0]))) : 0.f;
        maxcv[bi0 + t] = mc;
        degv[bi0 + t]  = (float)c;
        maskout[bi0 + t] = (mc > 0.5f) ? 1.f : 0.f;
    }
}

// ---------------------------------------------------------------------------
// Kernel 3: row MLP. 4 rows/block, 512 blocks x 512 thr; f=t&127, kq=t>>7.
// nf = (colsum - sum of A<=0 exception rows) / deg.
// ---------------------------------------------------------------------------
__global__ __launch_bounds__(512, 4) void k_mlp(
    const float* __restrict__ H, const float* __restrict__ csp,
    const unsigned long long* __restrict__ zmask,
    const float* __restrict__ degv, const float* __restrict__ maxcv,
    const float* __restrict__ rW1, const float* __restrict__ rb1,
    const float* __restrict__ rW2, const float* __restrict__ rb2,
    float* __restrict__ out) {
    __shared__ float sC[4][260];
    __shared__ float sP[3][4][F_];
    __shared__ float sL1[4][F_];
    __shared__ float sMC[4], sDegF[4];
    const int t  = threadIdx.x;
    const int f  = t & 127;
    const int kq = t >> 7;
    const int row0 = blockIdx.x * 4;
    const int b = row0 >> 9;

    {   // stage H + assembled nf (thread's row = kq)
        const int row = row0 + kq;
        sC[kq][f] = H[(size_t)row * F_ + f];
        float cs = 0.f;
        #pragma unroll
        for (int e = 0; e < 8; ++e)
            cs += csp[((size_t)b * 8 + e) * F_ + f];
        #pragma unroll
        for (int wv = 0; wv < 8; ++wv) {
            unsigned long long zb = zmask[(size_t)row * 8 + wv];
            while (zb) {                    // uniform loop; empty in practice
                const int j = __ffsll(zb) - 1;
                zb &= zb - 1;
                cs -= H[((size_t)b * N_ + wv * 64 + j) * F_ + f];
            }
        }
        sC[kq][F_ + f] = cs / fmaxf(degv[row], 1.f);
    }
    if (t < 4) {
        sMC[t]   = maxcv[row0 + t];
        sDegF[t] = degv[row0 + t];
    }
    __syncthreads();

    // ---- layer 1 ----
    float macc[4];
    {
        const float bias = rb1[f];
        #pragma unroll
        for (int r = 0; r < 4; ++r) macc[r] = (kq == 0) ? bias : 0.f;
    }
    const int k0 = kq * 64;
    #pragma unroll 4
    for (int k = k0; k < k0 + 64; ++k) {
        const float wv = rW1[(size_t)k * F_ + f];
        #pragma unroll
        for (int r = 0; r < 4; ++r) macc[r] = fmaf(sC[r][k], wv, macc[r]);
    }
    if (kq == 3) {
        const float w256 = rW1[(size_t)256 * F_ + f];
        #pragma unroll
        for (int r = 0; r < 4; ++r) macc[r] = fmaf(sMC[r], w256, macc[r]);
    }
    if (kq > 0) {
        #pragma unroll
        for (int r = 0; r < 4; ++r) sP[kq - 1][r][f] = macc[r];
    }
    __syncthreads();
    if (kq == 0) {
        #pragma unroll
        for (int r = 0; r < 4; ++r)
            sL1[r][f] = elu_f(macc[r] + sP[0][r][f] + sP[1][r][f] + sP[2][r][f]);
    }
    __syncthreads();

    // ---- layer 2 ----
    float macc2[4];
    {
        const float bias2 = rb2[f];
        #pragma unroll
        for (int r = 0; r < 4; ++r) macc2[r] = (kq == 0) ? bias2 : 0.f;
    }
    const int m0k = kq * 32;
    #pragma unroll 4
    for (int k = m0k; k < m0k + 32; ++k) {
        const float wv = rW2[(size_t)k * F_ + f];
        #pragma unroll
        for (int r = 0; r < 4; ++r) macc2[r] = fmaf(sL1[r][k], wv, macc2[r]);
    }
    if (kq > 0) {
        #pragma unroll
        for (int r = 0; r < 4; ++r) sP[kq - 1][r][f] = macc2[r];
    }
    __syncthreads();
    if (kq == 0) {
        #pragma unroll
        for (int r = 0; r < 4; ++r) {
            const int row = row0 + r;
            const float res = macc2[r] + sP[0][r][f] + sP[1][r][f] + sP[2][r][f];
            const bool upd = (sMC[r] > 0.5f) && (sDegF[r] > 0.f);
            out[(size_t)row * F_ + f] = upd ? res : sC[r][f];
        }
    }
}

// ---------------------------------------------------------------------------
extern "C" void kernel_launch(void* const* d_in, const int* in_sizes, int n_in,
                              void* d_out, int out_size, void* d_ws, size_t ws_size,
                              hipStream_t stream) {
    const float* H   = (const float*)d_in[0];
    const float* A   = (const float*)d_in[1];
    const float* dW1 = (const float*)d_in[2];
    const float* db1 = (const float*)d_in[3];
    const float* dW2 = (const float*)d_in[4];
    const float* db2 = (const float*)d_in[5];
    const float* rW1 = (const float*)d_in[6];
    const float* rb1 = (const float*)d_in[7];
    const float* rW2 = (const float*)d_in[8];
    const float* rb2 = (const float*)d_in[9];

    float* ws   = (float*)d_ws;
    float* Hi   = ws;                        // [BN][F]
    float* EHi  = Hi   + BN_ * F_;           // [BN][F]
    float* HjT  = EHi  + BN_ * F_;           // [B][F][N]
    float* csp  = HjT  + BN_ * F_;           // [B][8][F] colsum partials
    float* degv = csp  + B_ * 8 * F_;        // [BN]
    float* maxc = degv + BN_;                // [BN]
    unsigned long long* zmask =
        (unsigned long long*)(maxc + BN_);   // [BN][8]

    float* out      = (float*)d_out;         // [BN][F]
    float* mask_out = out + BN_ * F_;        // [BN]

    k_pre  <<<NG_ + 32, 512, 0, stream>>>(H, dW1, db1, Hi, EHi, HjT, csp);
    k_score<<<NG_, 512, 0, stream>>>(Hi, EHi, HjT, A, dW2, db2,
                                     maxc, degv, zmask, mask_out);
    k_mlp  <<<NG_, 512, 0, stream>>>(H, csp, zmask, degv, maxc,
                                     rW1, rb1, rW2, rb2, out);
}

// Round 15
// 40.867 us; speedup vs baseline: 3.9920x; 3.3066x over previous
//
#include <hip/hip_runtime.h>
#include <cmath>

#define B_ 4
#define N_ 512
#define F_ 128
#define BN_ (B_*N_)   // 2048
#define NG_ (BN_/4)   // 512 row-groups of 4

__device__ __forceinline__ float elu_f(float x) {
    return fmaxf(x, __expf(fminf(x, 0.f)) - 1.f);
}

// ---------------------------------------------------------------------------
// Kernel 1 (544 blocks x 512 thr):
//  blocks [0,512):   lin1 for 4 rows — Hi = H@dW1[:F]+db1, EHi = exp(Hi),
//                    HjT[b][f][n] = (H@dW1[F:])^T. K split across kq=t>>7.
//  blocks [512,544): colsum partials: csp[b][e][f] = sum of 64 H rows.
// ---------------------------------------------------------------------------
__global__ __launch_bounds__(512, 4) void k_pre(
    const float* __restrict__ H, const float* __restrict__ dW1,
    const float* __restrict__ db1,
    float* __restrict__ Hi, float* __restrict__ EHi, float* __restrict__ HjT,
    float* __restrict__ csp) {
    __shared__ float sH[4][F_];
    __shared__ float sPA[3][4][F_], sPB[3][4][F_];
    const int t = threadIdx.x;
    const int f = t & 127;
    const int kq = t >> 7;
    if (blockIdx.x < NG_) {
        // ---------------- lin1 ----------------
        const int row0 = blockIdx.x * 4;
        const int b  = row0 >> 9;
        const int n0 = row0 & 511;
        sH[kq][f] = H[(size_t)(row0 + kq) * F_ + f];
        __syncthreads();
        float accA[4] = {0.f,0.f,0.f,0.f}, accB[4] = {0.f,0.f,0.f,0.f};
        const int k0 = kq * 32;
        #pragma unroll 4
        for (int k = k0; k < k0 + 32; ++k) {
            const float wa = dW1[(size_t)k * F_ + f];
            const float wb = dW1[(size_t)(F_ + k) * F_ + f];
            #pragma unroll
            for (int r = 0; r < 4; ++r) {
                accA[r] = fmaf(sH[r][k], wa, accA[r]);
                accB[r] = fmaf(sH[r][k], wb, accB[r]);
            }
        }
        if (kq > 0) {
            #pragma unroll
            for (int r = 0; r < 4; ++r) {
                sPA[kq - 1][r][f] = accA[r];
                sPB[kq - 1][r][f] = accB[r];
            }
        }
        __syncthreads();
        if (kq == 0) {
            const float bias = db1[f];
            float bsum[4];
            #pragma unroll
            for (int r = 0; r < 4; ++r) {
                const float av = accA[r] + sPA[0][r][f] + sPA[1][r][f]
                               + sPA[2][r][f] + bias;
                Hi [(size_t)(row0 + r) * F_ + f] = av;
                EHi[(size_t)(row0 + r) * F_ + f] = __expf(av);
                bsum[r] = accB[r] + sPB[0][r][f] + sPB[1][r][f] + sPB[2][r][f];
            }
            float4 hv;
            hv.x = bsum[0]; hv.y = bsum[1]; hv.z = bsum[2]; hv.w = bsum[3];
            *reinterpret_cast<float4*>(HjT + ((size_t)b * F_ + f) * N_ + n0) = hv;
        }
    } else {
        // ---------------- colsum partial ----------------
        const int bx = blockIdx.x - NG_;   // 0..31
        const int b  = bx >> 3;
        const int e  = bx & 7;             // batch-eighth (64 rows)
        float s = 0.f;
        const float* hp = H + ((size_t)b * N_ + e * 64 + kq * 16) * F_ + f;
        #pragma unroll 4
        for (int jj = 0; jj < 16; ++jj) s += hp[(size_t)jj * F_];
        sH[kq][f] = s;
        __syncthreads();
        if (kq == 0)
            csp[((size_t)b * 8 + e) * F_ + f] =
                sH[0][f] + sH[1][f] + sH[2][f] + sH[3][f];
    }
}

// one f-slice: uniforms = component CP of (h0..h3, e0..e3, wq); 4 j's = HJ4.
#define SCORE_F(HJ4, CP) {                                                    \
    const float ejx = __expf((HJ4).x), ejy = __expf((HJ4).y),                 \
                ejz = __expf((HJ4).z), ejw = __expf((HJ4).w);                 \
    const float wv_ = wq.CP;                                                  \
    acc0.x = fmaf(__builtin_amdgcn_fmed3f(h0.CP + (HJ4).x, fmaf(e0.CP, ejx, -1.f), 0.f), wv_, acc0.x); \
    acc0.y = fmaf(__builtin_amdgcn_fmed3f(h0.CP + (HJ4).y, fmaf(e0.CP, ejy, -1.f), 0.f), wv_, acc0.y); \
    acc0.z = fmaf(__builtin_amdgcn_fmed3f(h0.CP + (HJ4).z, fmaf(e0.CP, ejz, -1.f), 0.f), wv_, acc0.z); \
    acc0.w = fmaf(__builtin_amdgcn_fmed3f(h0.CP + (HJ4).w, fmaf(e0.CP, ejw, -1.f), 0.f), wv_, acc0.w); \
    acc1.x = fmaf(__builtin_amdgcn_fmed3f(h1.CP + (HJ4).x, fmaf(e1.CP, ejx, -1.f), 0.f), wv_, acc1.x); \
    acc1.y = fmaf(__builtin_amdgcn_fmed3f(h1.CP + (HJ4).y, fmaf(e1.CP, ejy, -1.f), 0.f), wv_, acc1.y); \
    acc1.z = fmaf(__builtin_amdgcn_fmed3f(h1.CP + (HJ4).z, fmaf(e1.CP, ejz, -1.f), 0.f), wv_, acc1.z); \
    acc1.w = fmaf(__builtin_amdgcn_fmed3f(h1.CP + (HJ4).w, fmaf(e1.CP, ejw, -1.f), 0.f), wv_, acc1.w); \
    acc2.x = fmaf(__builtin_amdgcn_fmed3f(h2.CP + (HJ4).x, fmaf(e2.CP, ejx, -1.f), 0.f), wv_, acc2.x); \
    acc2.y = fmaf(__builtin_amdgcn_fmed3f(h2.CP + (HJ4).y, fmaf(e2.CP, ejy, -1.f), 0.f), wv_, acc2.y); \
    acc2.z = fmaf(__builtin_amdgcn_fmed3f(h2.CP + (HJ4).z, fmaf(e2.CP, ejz, -1.f), 0.f), wv_, acc2.z); \
    acc2.w = fmaf(__builtin_amdgcn_fmed3f(h2.CP + (HJ4).w, fmaf(e2.CP, ejw, -1.f), 0.f), wv_, acc2.w); \
    acc3.x = fmaf(__builtin_amdgcn_fmed3f(h3.CP + (HJ4).x, fmaf(e3.CP, ejx, -1.f), 0.f), wv_, acc3.x); \
    acc3.y = fmaf(__builtin_amdgcn_fmed3f(h3.CP + (HJ4).y, fmaf(e3.CP, ejy, -1.f), 0.f), wv_, acc3.y); \
    acc3.z = fmaf(__builtin_amdgcn_fmed3f(h3.CP + (HJ4).z, fmaf(e3.CP, ejz, -1.f), 0.f), wv_, acc3.z); \
    acc3.w = fmaf(__builtin_amdgcn_fmed3f(h3.CP + (HJ4).w, fmaf(e3.CP, ejw, -1.f), 0.f), wv_, acc3.w); }

// load the 4 hj rows of quad QQ into 4 NAMED float4s
#define LOADQ(QQ, B0, B1, B2, B3)                                             \
    B0 = *reinterpret_cast<const float4*>(hjq + (size_t)((QQ) * 4 + 0) * N_); \
    B1 = *reinterpret_cast<const float4*>(hjq + (size_t)((QQ) * 4 + 1) * N_); \
    B2 = *reinterpret_cast<const float4*>(hjq + (size_t)((QQ) * 4 + 2) * N_); \
    B3 = *reinterpret_cast<const float4*>(hjq + (size_t)((QQ) * 4 + 3) * N_);

#define COMPQ(QQ, B0, B1, B2, B3) {                                           \
    const int q_ = kq * 8 + (QQ);                                             \
    const float4 h0 = sU[q_][0], h1 = sU[q_][1], h2 = sU[q_][2], h3 = sU[q_][3]; \
    const float4 e0 = sU[q_][4], e1 = sU[q_][5], e2 = sU[q_][6], e3 = sU[q_][7]; \
    const float4 wq = sU[q_][8];                                              \
    SCORE_F(B0, x) SCORE_F(B1, y) SCORE_F(B2, z) SCORE_F(B3, w) }

// ---------------------------------------------------------------------------
// Kernel 2: score. 4 rows/block, 512 blocks x 512 thr.
// Thread (kq=t>>7, u=t&127) owns j-quad [4u..4u+3] x f-range [kq*32, +32).
// NO launch-bounds occupancy clamp: kernel needs ~110 VGPR; the (512,4)
// clamp forced a 64-VGPR cap -> 357 MB scratch spill (R12-R14).
// ---------------------------------------------------------------------------
__global__ __launch_bounds__(512) void k_score(
    const float* __restrict__ Hi, const float* __restrict__ EHi,
    const float* __restrict__ HjT, const float* __restrict__ A,
    const float* __restrict__ dW2, const float* __restrict__ db2,
    float* __restrict__ maxcv, float* __restrict__ degv,
    unsigned long long* __restrict__ zmask, float* __restrict__ maskout) {
    __shared__ float4 sU[32][9];          // [quad][0..3]=hi rows,[4..7]=Ei,[8]=w
    __shared__ float  sAcc[4][4][N_];     // [kq][r][j] partial logits (32 KB)
    __shared__ float  red_mx[8][4];
    __shared__ int    red_cnt[8][4];
    const int t = threadIdx.x;
    const int lane = t & 63;
    const int w = t >> 6;                 // wave 0..7
    const int u  = t & 127;               // j-quad owner
    const int kq = t >> 7;                // f-range owner
    const int bi0 = blockIdx.x * 4;
    const int b = bi0 >> 9;

    if (t < 288) {
        const int q  = t / 9;
        const int sl = t - q * 9;
        const float* src = (sl < 4) ? (Hi  + (size_t)(bi0 + sl)     * F_ + 4 * q)
                         : (sl < 8) ? (EHi + (size_t)(bi0 + sl - 4) * F_ + 4 * q)
                                    : (dW2 + 4 * q);
        sU[q][sl] = *reinterpret_cast<const float4*>(src);
    }
    float a_r[4];
    #pragma unroll
    for (int r = 0; r < 4; ++r) a_r[r] = A[(size_t)(bi0 + r) * N_ + t];

    // hj base: f = kq*32, j = 4u
    const float* __restrict__ hjq = HjT + (size_t)b * F_ * N_
                                  + (size_t)(kq * 32) * N_ + 4 * u;
    float4 hA0, hA1, hA2, hA3, hB0, hB1, hB2, hB3;
    LOADQ(0, hA0, hA1, hA2, hA3)
    __syncthreads();

    float4 acc0 = {0.f,0.f,0.f,0.f}, acc1 = {0.f,0.f,0.f,0.f};
    float4 acc2 = {0.f,0.f,0.f,0.f}, acc3 = {0.f,0.f,0.f,0.f};

    LOADQ(1, hB0, hB1, hB2, hB3)
    COMPQ(0, hA0, hA1, hA2, hA3)
    LOADQ(2, hA0, hA1, hA2, hA3)
    COMPQ(1, hB0, hB1, hB2, hB3)
    LOADQ(3, hB0, hB1, hB2, hB3)
    COMPQ(2, hA0, hA1, hA2, hA3)
    LOADQ(4, hA0, hA1, hA2, hA3)
    COMPQ(3, hB0, hB1, hB2, hB3)
    LOADQ(5, hB0, hB1, hB2, hB3)
    COMPQ(4, hA0, hA1, hA2, hA3)
    LOADQ(6, hA0, hA1, hA2, hA3)
    COMPQ(5, hB0, hB1, hB2, hB3)
    LOADQ(7, hB0, hB1, hB2, hB3)
    COMPQ(6, hA0, hA1, hA2, hA3)
    COMPQ(7, hB0, hB1, hB2, hB3)

    // spill partial sums: conflict-free b128 writes, [kq][r][j] layout
    *reinterpret_cast<float4*>(&sAcc[kq][0][4 * u]) = acc0;
    *reinterpret_cast<float4*>(&sAcc[kq][1][4 * u]) = acc1;
    *reinterpret_cast<float4*>(&sAcc[kq][2][4 * u]) = acc2;
    *reinterpret_cast<float4*>(&sAcc[kq][3][4 * u]) = acc3;
    __syncthreads();

    // back to t = j layout: sum over kq, mask, ballot, wave-reduce
    #pragma unroll
    for (int r = 0; r < 4; ++r) {
        const float a = a_r[r];
        const float sum = sAcc[0][r][t] + sAcc[1][r][t]
                        + sAcc[2][r][t] + sAcc[3][r][t];
        float mx = (a > 0.1f) ? sum : -INFINITY;
        #pragma unroll
        for (int off = 1; off < 64; off <<= 1)
            mx = fmaxf(mx, __shfl_xor(mx, off));
        const unsigned long long pos = __ballot(a > 0.f);
        const unsigned long long zb  = __ballot(a <= 0.f);
        if (lane == 0) {
            red_mx[w][r]  = mx;
            red_cnt[w][r] = (int)__popcll(pos);
            zmask[(size_t)(bi0 + r) * 8 + w] = zb;
        }
    }
    __syncthreads();
    if (t < 4) {
        float m = -INFINITY; int c = 0;
        #pragma unroll
        for (int ww = 0; ww < 8; ++ww) {
            m = fmaxf(m, red_mx[ww][t]);
            c += red_cnt[ww][t];
        }
        const float mc = (m > -INFINITY)
                       ? 1.f / (1.f + __expf(-(m + db2[0]))) : 0.f;
        maxcv[bi0 + t] = mc;
        degv[bi0 + t]  = (float)c;
        maskout[bi0 + t] = (mc > 0.5f) ? 1.f : 0.f;
    }
}

// ---------------------------------------------------------------------------
// Kernel 3: row MLP. 4 rows/block, 512 blocks x 512 thr; f=t&127, kq=t>>7.
// nf = (colsum - sum of A<=0 exception rows) / deg.
// ---------------------------------------------------------------------------
__global__ __launch_bounds__(512, 4) void k_mlp(
    const float* __restrict__ H, const float* __restrict__ csp,
    const unsigned long long* __restrict__ zmask,
    const float* __restrict__ degv, const float* __restrict__ maxcv,
    const float* __restrict__ rW1, const float* __restrict__ rb1,
    const float* __restrict__ rW2, const float* __restrict__ rb2,
    float* __restrict__ out) {
    __shared__ float sC[4][260];
    __shared__ float sP[3][4][F_];
    __shared__ float sL1[4][F_];
    __shared__ float sMC[4], sDegF[4];
    const int t  = threadIdx.x;
    const int f  = t & 127;
    const int kq = t >> 7;
    const int row0 = blockIdx.x * 4;
    const int b = row0 >> 9;

    {   // stage H + assembled nf (thread's row = kq)
        const int row = row0 + kq;
        sC[kq][f] = H[(size_t)row * F_ + f];
        float cs = 0.f;
        #pragma unroll
        for (int e = 0; e < 8; ++e)
            cs += csp[((size_t)b * 8 + e) * F_ + f];
        #pragma unroll
        for (int wv = 0; wv < 8; ++wv) {
            unsigned long long zb = zmask[(size_t)row * 8 + wv];
            while (zb) {                    // uniform loop; empty in practice
                const int j = __ffsll(zb) - 1;
                zb &= zb - 1;
                cs -= H[((size_t)b * N_ + wv * 64 + j) * F_ + f];
            }
        }
        sC[kq][F_ + f] = cs / fmaxf(degv[row], 1.f);
    }
    if (t < 4) {
        sMC[t]   = maxcv[row0 + t];
        sDegF[t] = degv[row0 + t];
    }
    __syncthreads();

    // ---- layer 1 ----
    float macc[4];
    {
        const float bias = rb1[f];
        #pragma unroll
        for (int r = 0; r < 4; ++r) macc[r] = (kq == 0) ? bias : 0.f;
    }
    const int k0 = kq * 64;
    #pragma unroll 4
    for (int k = k0; k < k0 + 64; ++k) {
        const float wv = rW1[(size_t)k * F_ + f];
        #pragma unroll
        for (int r = 0; r < 4; ++r) macc[r] = fmaf(sC[r][k], wv, macc[r]);
    }
    if (kq == 3) {
        const float w256 = rW1[(size_t)256 * F_ + f];
        #pragma unroll
        for (int r = 0; r < 4; ++r) macc[r] = fmaf(sMC[r], w256, macc[r]);
    }
    if (kq > 0) {
        #pragma unroll
        for (int r = 0; r < 4; ++r) sP[kq - 1][r][f] = macc[r];
    }
    __syncthreads();
    if (kq == 0) {
        #pragma unroll
        for (int r = 0; r < 4; ++r)
            sL1[r][f] = elu_f(macc[r] + sP[0][r][f] + sP[1][r][f] + sP[2][r][f]);
    }
    __syncthreads();

    // ---- layer 2 ----
    float macc2[4];
    {
        const float bias2 = rb2[f];
        #pragma unroll
        for (int r = 0; r < 4; ++r) macc2[r] = (kq == 0) ? bias2 : 0.f;
    }
    const int m0k = kq * 32;
    #pragma unroll 4
    for (int k = m0k; k < m0k + 32; ++k) {
        const float wv = rW2[(size_t)k * F_ + f];
        #pragma unroll
        for (int r = 0; r < 4; ++r) macc2[r] = fmaf(sL1[r][k], wv, macc2[r]);
    }
    if (kq > 0) {
        #pragma unroll
        for (int r = 0; r < 4; ++r) sP[kq - 1][r][f] = macc2[r];
    }
    __syncthreads();
    if (kq == 0) {
        #pragma unroll
        for (int r = 0; r < 4; ++r) {
            const int row = row0 + r;
            const float res = macc2[r] + sP[0][r][f] + sP[1][r][f] + sP[2][r][f];
            const bool upd = (sMC[r] > 0.5f) && (sDegF[r] > 0.f);
            out[(size_t)row * F_ + f] = upd ? res : sC[r][f];
        }
    }
}

// ---------------------------------------------------------------------------
extern "C" void kernel_launch(void* const* d_in, const int* in_sizes, int n_in,
                              void* d_out, int out_size, void* d_ws, size_t ws_size,
                              hipStream_t stream) {
    const float* H   = (const float*)d_in[0];
    const float* A   = (const float*)d_in[1];
    const float* dW1 = (const float*)d_in[2];
    const float* db1 = (const float*)d_in[3];
    const float* dW2 = (const float*)d_in[4];
    const float* db2 = (const float*)d_in[5];
    const float* rW1 = (const float*)d_in[6];
    const float* rb1 = (const float*)d_in[7];
    const float* rW2 = (const float*)d_in[8];
    const float* rb2 = (const float*)d_in[9];

    float* ws   = (float*)d_ws;
    float* Hi   = ws;                        // [BN][F]
    float* EHi  = Hi   + BN_ * F_;           // [BN][F]
    float* HjT  = EHi  + BN_ * F_;           // [B][F][N]
    float* csp  = HjT  + BN_ * F_;           // [B][8][F] colsum partials
    float* degv = csp  + B_ * 8 * F_;        // [BN]
    float* maxc = degv + BN_;                // [BN]
    unsigned long long* zmask =
        (unsigned long long*)(maxc + BN_);   // [BN][8]

    float* out      = (float*)d_out;         // [BN][F]
    float* mask_out = out + BN_ * F_;        // [BN]

    k_pre  <<<NG_ + 32, 512, 0, stream>>>(H, dW1, db1, Hi, EHi, HjT, csp);
    k_score<<<NG_, 512, 0, stream>>>(Hi, EHi, HjT, A, dW2, db2,
                                     maxc, degv, zmask, mask_out);
    k_mlp  <<<NG_, 512, 0, stream>>>(H, csp, zmask, degv, maxc,
                                     rW1, rb1, rW2, rb2, out);
}